// Round 10
// baseline (141.811 us; speedup 1.0000x reference)
//
#include <hip/hip_runtime.h>
#include <math.h>
#include <stdint.h>

#define B    4
#define O    64
#define TF   1025
#define NF   1024
#define TOUT 262144

#define C32POS ((float)(1024.0 / 262143.0))   // == 2^-8 + 2^-26 exactly
#define C2PI32 ((float)(2.0 * M_PI / 44100.0))
#define PI32   ((float)M_PI)

// fl32(x0*(1-w)) + fl32(x1*w), contraction-proof (numpy op order, no fma)
__device__ __forceinline__ float lin32(float x0, float x1, float w) {
    float omw = 1.0f - w;
    float t1 = x0 * omw;
    float t2 = x1 * w;
    asm volatile("" : "+v"(t1), "+v"(t2));
    return t1 + t2;
}

__device__ __forceinline__ float init32(float uu) {
    return ((uu * 2.0f) - 1.0f) * PI32;   // fl32(3.14159265) == fl32(pi)
}

// numpy-f32 geometry: pos = fl32(n*c32); i = clip(floor(pos),0,1023); w = pos-i
__device__ __forceinline__ void geom(int n, int& i, float& w) {
    float pos = (float)n * C32POS;
    i = (int)pos;
    if (i > NF - 1) i = NF - 1;
    w = pos - (float)i;
}

// ---- k1: bit-exact f32 fs table + frame amps, chain-major (np-faithful) ---
__global__ void k1(const float* __restrict__ f0, const float* __restrict__ master,
                   const float* __restrict__ ov,
                   float* __restrict__ FS, float* __restrict__ Aamp) {
    int f = blockIdx.x, b = blockIdx.y, o = threadIdx.x;
    __shared__ float vals[O];
    __shared__ float sden;
    float f0v = f0[b * TF + f];
    float fs  = (f0v * (float)(o + 1)) * C2PI32;
    FS[(b * O + o) * TF + f] = fs;
    float val = (fs > PI32) ? 0.0f : ov[(b * O + o) * TF + f];
    vals[o] = val;
    __syncthreads();
    if (o == 0) {                          // numpy axis-reduce: sequential in o
        float d = 0.0f;
        for (int i = 0; i < O; ++i) d = d + vals[i];
        sden = d;
    }
    __syncthreads();
    Aamp[(b * O + o) * TF + f] = (val / sden) * master[b * TF + f];
}

// ---- kT: per-frame f64 totals of the f32 summands. lane = harmonic --------
__global__ void __launch_bounds__(64) kT(const float* __restrict__ FS,
                                         const float* __restrict__ u,
                                         double* __restrict__ T) {  // [256][NF]
    int f = blockIdx.x, b = blockIdx.y, o = threadIdx.x;
    int chain = b * O + o;
    float fs0 = FS[chain * TF + f], fs1 = FS[chain * TF + f + 1];
    double s = 0.0;
    for (int k = 0; k < 256; ++k) {
        int n = f * 256 + k;
        int i; float w; geom(n, i, w);
        // i is f (normal; incl. w==1.0 clip edge) or f+1 with w==0 -> fs1 exact
        float v = (i == f) ? lin32(fs0, fs1, w) : fs1;
        if (n == 0) v = init32(u[chain]);
        s += (double)v;                    // f64: order-insensitive to ~1e-10
    }
    T[(size_t)chain * NF + f] = s;
}

// ---- kScan: per-chain exclusive scan of the 1024 frame totals (f64) -------
__global__ void __launch_bounds__(256) kScan(const double* __restrict__ T,
                                             double* __restrict__ C) { // [256][NF]
    int chain = blockIdx.x, t = threadIdx.x;
    const double* Tc = T + (size_t)chain * NF;
    double v[4], tot = 0.0;
    #pragma unroll
    for (int m = 0; m < 4; ++m) { v[m] = Tc[t * 4 + m]; tot += v[m]; }
    __shared__ double sb[256];
    sb[t] = tot;
    __syncthreads();
    for (int off = 1; off < 256; off <<= 1) {
        double x = (t >= off) ? sb[t - off] : 0.0;
        __syncthreads();
        sb[t] += x;
        __syncthreads();
    }
    double run = sb[t] - tot;              // exclusive prefix for this thread
    double* Cc = C + (size_t)chain * NF;
    #pragma unroll
    for (int m = 0; m < 4; ++m) { Cc[t * 4 + m] = run; run += v[m]; }
}

// ---- kC: synth. f64 phase throughout; sin at the very end -----------------
__global__ void __launch_bounds__(64) kC(const float* __restrict__ FS,
                                         const float* __restrict__ Aamp,
                                         const float* __restrict__ u,
                                         const double* __restrict__ C,
                                         float* __restrict__ out) {
    int f = blockIdx.x, b = blockIdx.y, o = threadIdx.x;
    int chain = b * O + o;
    float fs0 = FS[chain * TF + f], fs1 = FS[chain * TF + f + 1];
    float a0  = Aamp[chain * TF + f], a1 = Aamp[chain * TF + f + 1];
    double S = C[(size_t)chain * NF + f];  // phase before this frame's samples
    __shared__ float buf[256];
    const double INV2PI = 0.15915494309189535;
    for (int k = 0; k < 256; ++k) {
        int n = f * 256 + k;
        int i; float w; geom(n, i, w);
        float v, amp;
        if (i == f) { v = lin32(fs0, fs1, w); amp = lin32(a0, a1, w); }
        else        { v = fs1;                amp = a1; }  // round-up edge, w==0
        if (n == 0) v = init32(u[chain]);
        S += (double)v;                    // matches kT's summand bits exactly
        double rev = S * INV2PI;           // f64 phase -> revolutions
        double fr  = rev - rint(rev);      // [-0.5, 0.5], ~1e-11 accurate
        float term = __builtin_amdgcn_sinf((float)fr) * amp;  // sin(2*pi*fr)
        #pragma unroll
        for (int d = 32; d; d >>= 1) term += __shfl_xor(term, d, 64);
        if (o == 0) buf[k] = term;
    }
    __syncthreads();
    float* ob = out + (size_t)b * TOUT + f * 256;
    for (int k = o; k < 256; k += 64) ob[k] = buf[k];   // coalesced store
}

extern "C" void kernel_launch(void* const* d_in, const int* in_sizes, int n_in,
                              void* d_out, int out_size, void* d_ws, size_t ws_size,
                              hipStream_t stream) {
    const float* f0     = (const float*)d_in[0];
    const float* master = (const float*)d_in[1];
    const float* ov     = (const float*)d_in[2];
    const float* u      = (const float*)d_in[3];
    float* out = (float*)d_out;

    // ws: FS (1.05MB) | Aamp (1.05MB) | T (2MB f64) | C (2MB f64)
    float*  FS   = (float*)d_ws;
    float*  Aamp = FS + (size_t)B * O * TF;
    double* T    = (double*)(Aamp + (size_t)B * O * TF);
    double* C    = T + (size_t)B * O * NF;

    k1   <<<dim3(TF, B), 64,  0, stream>>>(f0, master, ov, FS, Aamp);
    kT   <<<dim3(NF, B), 64,  0, stream>>>(FS, u, T);
    kScan<<<B * O,       256, 0, stream>>>(T, C);
    kC   <<<dim3(NF, B), 64,  0, stream>>>(FS, Aamp, u, C, out);
}

// Round 11
// 134.150 us; speedup vs baseline: 1.0571x; 1.0571x over previous
//
#include <hip/hip_runtime.h>
#include <math.h>
#include <stdint.h>

#define B    4
#define O    64
#define TF   1025
#define NF   1024
#define NF2  2048      // half-frames (128-sample granularity)
#define TOUT 262144

#define C32POS ((float)(1024.0 / 262143.0))   // == 2^-8 + 2^-26 exactly
#define C2PI32 ((float)(2.0 * M_PI / 44100.0))
#define PI32   ((float)M_PI)

// fl32(x0*(1-w)) + fl32(x1*w), contraction-proof (numpy op order, no fma)
__device__ __forceinline__ float lin32(float x0, float x1, float w) {
    float omw = 1.0f - w;
    float t1 = x0 * omw;
    float t2 = x1 * w;
    asm volatile("" : "+v"(t1), "+v"(t2));
    return t1 + t2;
}

__device__ __forceinline__ float init32(float uu) {
    return ((uu * 2.0f) - 1.0f) * PI32;   // fl32(3.14159265) == fl32(pi)
}

// numpy-f32 geometry: pos = fl32(n*c32); i = clip(floor(pos),0,1023); w = pos-i
__device__ __forceinline__ void geom(int n, int& i, float& w) {
    float pos = (float)n * C32POS;
    i = (int)pos;
    if (i > NF - 1) i = NF - 1;
    w = pos - (float)i;
}

// ---- k1: bit-exact f32 fs table + frame amps, chain-major (np-faithful) ---
__global__ void k1(const float* __restrict__ f0, const float* __restrict__ master,
                   const float* __restrict__ ov,
                   float* __restrict__ FS, float* __restrict__ Aamp) {
    int f = blockIdx.x, b = blockIdx.y, o = threadIdx.x;
    __shared__ float vals[O];
    __shared__ float sden;
    float f0v = f0[b * TF + f];
    float fs  = (f0v * (float)(o + 1)) * C2PI32;
    FS[(b * O + o) * TF + f] = fs;
    float val = (fs > PI32) ? 0.0f : ov[(b * O + o) * TF + f];
    vals[o] = val;
    __syncthreads();
    if (o == 0) {                          // sequential in o (as in passing R10)
        float d = 0.0f;
        for (int i = 0; i < O; ++i) d = d + vals[i];
        sden = d;
    }
    __syncthreads();
    Aamp[(b * O + o) * TF + f] = (val / sden) * master[b * TF + f];
}

// ---- kT: per-HALF-frame f64 totals of the f32 summands --------------------
// thread = (o, h); 128 sequential summands each. Same summand bits as R10.
__global__ void __launch_bounds__(128) kT(const float* __restrict__ FS,
                                          const float* __restrict__ u,
                                          double* __restrict__ T) { // [256][NF2]
    int f = blockIdx.x, b = blockIdx.y;
    int t = threadIdx.x;
    int o = t & 63, h = t >> 6;
    int chain = b * O + o;
    float fs0 = FS[chain * TF + f], fs1 = FS[chain * TF + f + 1];
    int base = f * 256 + h * 128;
    double s = 0.0;
    for (int k = 0; k < 128; ++k) {
        int n = base + k;
        int i; float w; geom(n, i, w);
        float v = (i == f) ? lin32(fs0, fs1, w) : fs1;   // round-up edge: w==0
        if (n == 0) v = init32(u[chain]);
        s += (double)v;
    }
    T[(size_t)chain * NF2 + f * 2 + h] = s;
}

// ---- kScan: per-chain exclusive scan of 2048 half-frame totals (f64) ------
__global__ void __launch_bounds__(256) kScan(const double* __restrict__ T,
                                             double* __restrict__ C) { // [256][NF2]
    int chain = blockIdx.x, t = threadIdx.x;
    const double* Tc = T + (size_t)chain * NF2;
    double v[8], tot = 0.0;
    #pragma unroll
    for (int m = 0; m < 8; ++m) { v[m] = Tc[t * 8 + m]; tot += v[m]; }
    __shared__ double sb[256];
    sb[t] = tot;
    __syncthreads();
    for (int off = 1; off < 256; off <<= 1) {
        double x = (t >= off) ? sb[t - off] : 0.0;
        __syncthreads();
        sb[t] += x;
        __syncthreads();
    }
    double run = sb[t] - tot;              // exclusive prefix for this thread
    double* Cc = C + (size_t)chain * NF2;
    #pragma unroll
    for (int m = 0; m < 8; ++m) { Cc[t * 8 + m] = run; run += v[m]; }
}

// ---- kC: synth. 4 waves/block, each wave owns a 32-sample window ----------
// Pass1: window summands -> regs + f64 window sum (shared via LDS).
// Pass2: identical sequential f64 chain + identical mod-2pi/sin/amp/butterfly
// as the R10-passing kernel. Only the START association changes (~1e-10 rad).
__global__ void __launch_bounds__(256) kC(const float* __restrict__ FS,
                                          const float* __restrict__ Aamp,
                                          const float* __restrict__ u,
                                          const double* __restrict__ C,
                                          float* __restrict__ out) {
    int fh = blockIdx.x, b = blockIdx.y;
    int f  = fh >> 1;
    int t  = threadIdx.x;
    int o  = t & 63, q = t >> 6;          // lane = harmonic, wave = window
    int chain = b * O + o;
    int base  = fh * 128 + q * 32;        // global sample index of window start

    float fs0 = FS[chain * TF + f], fs1 = FS[chain * TF + f + 1];
    float a0  = Aamp[chain * TF + f], a1 = Aamp[chain * TF + f + 1];

    // pass 1: summands into registers (static indexing), f64 window sum
    float v[32];
    double W = 0.0;
    #pragma unroll
    for (int k = 0; k < 32; ++k) {
        int n = base + k;
        int i; float w; geom(n, i, w);
        float vv = (i == f) ? lin32(fs0, fs1, w) : fs1;
        if (n == 0) vv = init32(u[chain]);
        v[k] = vv;
        W += (double)vv;
    }

    __shared__ double wsum[4][O];
    __shared__ float  buf[128];
    wsum[q][o] = W;
    __syncthreads();

    double S = C[(size_t)chain * NF2 + fh];   // phase before this half-frame
    #pragma unroll
    for (int qq = 0; qq < 3; ++qq)            // sequential q'=0,1,2
        if (qq < q) S += wsum[qq][o];

    const double INV2PI = 0.15915494309189535;
    #pragma unroll
    for (int k = 0; k < 32; ++k) {
        int n = base + k;
        int i; float w; geom(n, i, w);
        S += (double)v[k];                    // same chain order as R10
        double rev = S * INV2PI;
        double fr  = rev - rint(rev);         // [-0.5, 0.5] revolutions
        float amp  = (i == f) ? lin32(a0, a1, w) : a1;
        float term = __builtin_amdgcn_sinf((float)fr) * amp;  // sin(2*pi*fr)
        #pragma unroll
        for (int d = 32; d; d >>= 1) term += __shfl_xor(term, d, 64);
        if (o == 0) buf[q * 32 + k] = term;
    }
    __syncthreads();
    if (t < 128) out[(size_t)b * TOUT + fh * 128 + t] = buf[t];
}

extern "C" void kernel_launch(void* const* d_in, const int* in_sizes, int n_in,
                              void* d_out, int out_size, void* d_ws, size_t ws_size,
                              hipStream_t stream) {
    const float* f0     = (const float*)d_in[0];
    const float* master = (const float*)d_in[1];
    const float* ov     = (const float*)d_in[2];
    const float* u      = (const float*)d_in[3];
    float* out = (float*)d_out;

    // ws: FS (1.05MB) | Aamp (1.05MB) | T (4MB f64) | C (4MB f64)
    float*  FS   = (float*)d_ws;
    float*  Aamp = FS + (size_t)B * O * TF;
    double* T    = (double*)(Aamp + (size_t)B * O * TF);
    double* C    = T + (size_t)B * O * NF2;

    k1   <<<dim3(TF, B),  64,  0, stream>>>(f0, master, ov, FS, Aamp);
    kT   <<<dim3(NF, B),  128, 0, stream>>>(FS, u, T);
    kScan<<<B * O,        256, 0, stream>>>(T, C);
    kC   <<<dim3(NF2, B), 256, 0, stream>>>(FS, Aamp, u, C, out);
}

// Round 12
// 94.796 us; speedup vs baseline: 1.4960x; 1.4151x over previous
//
#include <hip/hip_runtime.h>
#include <math.h>
#include <stdint.h>

#define B    4
#define O    64
#define TF   1025
#define NF   1024
#define NF2  2048      // half-frames (128-sample granularity)
#define TOUT 262144

#define C32POS ((float)(1024.0 / 262143.0))   // == 2^-8 + 2^-26 exactly
#define C2PI32 ((float)(2.0 * M_PI / 44100.0))
#define PI32   ((float)M_PI)
#define INV2PI32 ((float)(1.0 / (2.0 * M_PI)))

// fl32(x0*(1-w)) + fl32(x1*w), contraction-proof (numpy op order, no fma)
__device__ __forceinline__ float lin32(float x0, float x1, float w) {
    float omw = 1.0f - w;
    float t1 = x0 * omw;
    float t2 = x1 * w;
    asm volatile("" : "+v"(t1), "+v"(t2));
    return t1 + t2;
}

__device__ __forceinline__ float init32(float uu) {
    return ((uu * 2.0f) - 1.0f) * PI32;   // fl32(3.14159265) == fl32(pi)
}

// numpy-f32 geometry: pos = fl32(n*c32); i = clip(floor(pos),0,1023); w = pos-i
__device__ __forceinline__ void geom(int n, int& i, float& w) {
    float pos = (float)n * C32POS;
    i = (int)pos;
    if (i > NF - 1) i = NF - 1;
    w = pos - (float)i;
}

// canonical GCN DPP 64-lane add-reduce; total lands in lane 63 (VALU pipe)
__device__ __forceinline__ float dpp_sum64(float x) {
    int v = __float_as_int(x);
    int t;
    t = __builtin_amdgcn_update_dpp(0, v, 0x111, 0xF, 0xF, true);  // row_shr:1
    v = __float_as_int(__int_as_float(v) + __int_as_float(t));
    t = __builtin_amdgcn_update_dpp(0, v, 0x112, 0xF, 0xF, true);  // row_shr:2
    v = __float_as_int(__int_as_float(v) + __int_as_float(t));
    t = __builtin_amdgcn_update_dpp(0, v, 0x114, 0xF, 0xF, true);  // row_shr:4
    v = __float_as_int(__int_as_float(v) + __int_as_float(t));
    t = __builtin_amdgcn_update_dpp(0, v, 0x118, 0xF, 0xF, true);  // row_shr:8
    v = __float_as_int(__int_as_float(v) + __int_as_float(t));
    t = __builtin_amdgcn_update_dpp(0, v, 0x142, 0xA, 0xF, true);  // bcast15 -> rows 1,3
    v = __float_as_int(__int_as_float(v) + __int_as_float(t));
    t = __builtin_amdgcn_update_dpp(0, v, 0x143, 0xC, 0xF, true);  // bcast31 -> rows 2,3
    v = __float_as_int(__int_as_float(v) + __int_as_float(t));
    return __int_as_float(v);
}

// ---- k1: bit-exact f32 fs table + frame amps, chain-major (np-faithful) ---
__global__ void k1(const float* __restrict__ f0, const float* __restrict__ master,
                   const float* __restrict__ ov,
                   float* __restrict__ FS, float* __restrict__ Aamp) {
    int f = blockIdx.x, b = blockIdx.y, o = threadIdx.x;
    __shared__ float vals[O];
    __shared__ float sden;
    float f0v = f0[b * TF + f];
    float fs  = (f0v * (float)(o + 1)) * C2PI32;
    FS[(b * O + o) * TF + f] = fs;
    float val = (fs > PI32) ? 0.0f : ov[(b * O + o) * TF + f];
    vals[o] = val;
    __syncthreads();
    if (o == 0) {                          // sequential in o (as in passing R10)
        float d = 0.0f;
        for (int i = 0; i < O; ++i) d = d + vals[i];
        sden = d;
    }
    __syncthreads();
    Aamp[(b * O + o) * TF + f] = (val / sden) * master[b * TF + f];
}

// ---- kT: per-HALF-frame f64 totals of the f32 summands (R11 bits) ---------
__global__ void __launch_bounds__(128) kT(const float* __restrict__ FS,
                                          const float* __restrict__ u,
                                          double* __restrict__ T) { // [256][NF2]
    int f = blockIdx.x, b = blockIdx.y;
    int t = threadIdx.x;
    int o = t & 63, h = t >> 6;
    int chain = b * O + o;
    float fs0 = FS[chain * TF + f], fs1 = FS[chain * TF + f + 1];
    int base = f * 256 + h * 128;
    double s = 0.0;
    for (int k = 0; k < 128; ++k) {
        int n = base + k;
        int i; float w; geom(n, i, w);
        float v = (i == f) ? lin32(fs0, fs1, w) : fs1;   // round-up edge: w==0
        if (n == 0) v = init32(u[chain]);
        s += (double)v;
    }
    T[(size_t)chain * NF2 + f * 2 + h] = s;
}

// ---- kScan: per-chain exclusive scan of 2048 half-frame totals (f64) ------
__global__ void __launch_bounds__(256) kScan(const double* __restrict__ T,
                                             double* __restrict__ C) { // [256][NF2]
    int chain = blockIdx.x, t = threadIdx.x;
    const double* Tc = T + (size_t)chain * NF2;
    double v[8], tot = 0.0;
    #pragma unroll
    for (int m = 0; m < 8; ++m) { v[m] = Tc[t * 8 + m]; tot += v[m]; }
    __shared__ double sb[256];
    sb[t] = tot;
    __syncthreads();
    for (int off = 1; off < 256; off <<= 1) {
        double x = (t >= off) ? sb[t - off] : 0.0;
        __syncthreads();
        sb[t] += x;
        __syncthreads();
    }
    double run = sb[t] - tot;              // exclusive prefix for this thread
    double* Cc = C + (size_t)chain * NF2;
    #pragma unroll
    for (int m = 0; m < 8; ++m) { Cc[t * 8 + m] = run; run += v[m]; }
}

// ---- kC: synth. 4 independent waves/block; 1 wave = 1 half-frame ----------
// f64-exact start phase; f32 revolution-wrapped walk within the 128 samples
// (drift <= ~2e-6 rad); DPP VALU reduce; readlane+cndmask stash; coalesced
// 64-lane stores. No LDS, no __syncthreads.
__global__ void __launch_bounds__(256) kC(const float* __restrict__ FS,
                                          const float* __restrict__ Aamp,
                                          const float* __restrict__ u,
                                          const double* __restrict__ C,
                                          float* __restrict__ out) {
    int t = threadIdx.x;
    int o = t & 63, wv = t >> 6;
    int task = blockIdx.x * 4 + wv;       // 0..8191
    int fh = task & (NF2 - 1);            // half-frame
    int b  = task >> 11;
    int f  = fh >> 1;
    int chain = b * O + o;

    float fs0 = FS[chain * TF + f], fs1 = FS[chain * TF + f + 1];
    float a0  = Aamp[chain * TF + f], a1 = Aamp[chain * TF + f + 1];

    double S0   = C[(size_t)chain * NF2 + fh];   // f64-exact start phase (rad)
    double rev0 = S0 * 0.15915494309189535;
    float  fr   = (float)(rev0 - rint(rev0));    // fractional revolutions
    float  ff   = (float)f;
    int nbase = fh * 128;

    #pragma unroll
    for (int half = 0; half < 2; ++half) {
        float stash = 0.0f;
        #pragma unroll 8
        for (int kk = 0; kk < 64; ++kk) {
            int n = nbase + half * 64 + kk;
            float pos = (float)n * C32POS;
            float fi  = floorf(pos);
            fi = fminf(fi, 1023.0f);
            float w   = pos - fi;
            bool hit  = (fi == ff);
            float v   = hit ? lin32(fs0, fs1, w) : fs1;  // round-up edge: w==0
            float amp = hit ? lin32(a0, a1, w)  : a1;
            if (n == 0) v = init32(u[chain]);            // wave-uniform branch
            fr += v * INV2PI32;                          // f32 rev walk
            fr -= rintf(fr);                             // wrap to [-0.5,0.5]
            float term = __builtin_amdgcn_sinf(fr) * amp;  // sin(2*pi*fr)
            float red  = dpp_sum64(term);                // lane 63 = sum over o
            float sv = __int_as_float(
                __builtin_amdgcn_readlane(__float_as_int(red), 63));
            if (o == kk) stash = sv;                     // v_cmp + cndmask
        }
        out[(size_t)b * TOUT + nbase + half * 64 + o] = stash;  // 256B store
    }
}

extern "C" void kernel_launch(void* const* d_in, const int* in_sizes, int n_in,
                              void* d_out, int out_size, void* d_ws, size_t ws_size,
                              hipStream_t stream) {
    const float* f0     = (const float*)d_in[0];
    const float* master = (const float*)d_in[1];
    const float* ov     = (const float*)d_in[2];
    const float* u      = (const float*)d_in[3];
    float* out = (float*)d_out;

    // ws: FS (1.05MB) | Aamp (1.05MB) | T (4MB f64) | C (4MB f64)
    float*  FS   = (float*)d_ws;
    float*  Aamp = FS + (size_t)B * O * TF;
    double* T    = (double*)(Aamp + (size_t)B * O * TF);
    double* C    = T + (size_t)B * O * NF2;

    k1   <<<dim3(TF, B),      64,  0, stream>>>(f0, master, ov, FS, Aamp);
    kT   <<<dim3(NF, B),      128, 0, stream>>>(FS, u, T);
    kScan<<<B * O,            256, 0, stream>>>(T, C);
    kC   <<<(NF2 * B) / 4,    256, 0, stream>>>(FS, Aamp, u, C, out);
}

// Round 13
// 71.054 us; speedup vs baseline: 1.9958x; 1.3341x over previous
//
#include <hip/hip_runtime.h>
#include <math.h>
#include <stdint.h>

#define B    4
#define O    64
#define TF   1025
#define NF   1024
#define NF2  2048      // half-frames (128 samples: kC window)
#define NQ   4096      // quarter-frames (64 samples: anchor granularity)
#define TOUT 262144

#define C32POS  ((float)(1024.0 / 262143.0))   // == 2^-8 + 2^-26 exactly
#define C2PI32  ((float)(2.0 * M_PI / 44100.0))
#define PI32    ((float)M_PI)
#define INV2PI32 ((float)(1.0 / (2.0 * M_PI)))
#define INV2PI64 0.15915494309189535

// fl32(x0*(1-w)) + fl32(x1*w), contraction-proof (numpy op order, no fma).
// NOTE: at w==1.0 this returns fs1 BIT-EXACTLY (t1=+0, t2=fs1) -> covers the
// pos-round-up and n=262143 clip edges with no branch.
__device__ __forceinline__ float lin32(float x0, float x1, float w) {
    float omw = 1.0f - w;
    float t1 = x0 * omw;
    float t2 = x1 * w;
    asm volatile("" : "+v"(t1), "+v"(t2));
    return t1 + t2;
}

__device__ __forceinline__ float init32(float uu) {
    return ((uu * 2.0f) - 1.0f) * PI32;   // fl32(3.14159265) == fl32(pi)
}

__device__ __forceinline__ float rl(float v, int l) {   // readlane (const l)
    return __int_as_float(__builtin_amdgcn_readlane(__float_as_int(v), l));
}

__device__ __forceinline__ float fract32(float x) {
#if __has_builtin(__builtin_amdgcn_fractf)
    return __builtin_amdgcn_fractf(x);
#else
    return x - floorf(x);
#endif
}

// ---- k1: bit-exact f32 fs table + frame amps (butterfly denominator) ------
__global__ void __launch_bounds__(64) k1(
        const float* __restrict__ f0, const float* __restrict__ master,
        const float* __restrict__ ov,
        float* __restrict__ FS, float* __restrict__ Aamp) {
    int f = blockIdx.x, b = blockIdx.y, o = threadIdx.x;
    float f0v = f0[b * TF + f];
    float fs  = (f0v * (float)(o + 1)) * C2PI32;
    FS[(b * O + o) * TF + f] = fs;
    float val = (fs > PI32) ? 0.0f : ov[(b * O + o) * TF + f];
    float den = val;
    #pragma unroll
    for (int d = 32; d; d >>= 1) den += __shfl_xor(den, d, 64);
    Aamp[(b * O + o) * TF + f] = (val / den) * master[b * TF + f];
}

// ---- kT: per-QUARTER-frame f64 totals of bit-exact f32 summands -----------
// thread = (o, q); 64 sequential summands each. Bits identical to R12's kT.
__global__ void __launch_bounds__(256) kT(const float* __restrict__ FS,
                                          const float* __restrict__ u,
                                          double* __restrict__ T) { // [256][NQ]
    int f = blockIdx.x, b = blockIdx.y;
    int t = threadIdx.x;
    int o = t & 63, q = t >> 6;
    int chain = b * O + o;
    float fs0 = FS[chain * TF + f], fs1 = FS[chain * TF + f + 1];
    float ff = (float)f;
    float fn = (float)(f * 256 + q * 64);
    double s = 0.0;
    #pragma unroll 8
    for (int k = 0; k < 64; ++k) {
        float pos = fn * C32POS;
        asm volatile("" : "+v"(pos));          // forbid mul+sub fma-contraction
        float w = pos - ff;
        s += (double)lin32(fs0, fs1, w);       // w==1.0 edge -> fs1 exact
        fn += 1.0f;
    }
    if (f == 0 && q == 0)                      // replace summand 0 (==fs0) by init
        s = s - (double)fs0 + (double)init32(u[chain]);
    T[(size_t)chain * NQ + f * 4 + q] = s;
}

// ---- kScan: per-chain exclusive scan of 4096 quarter totals (f64) ---------
__global__ void __launch_bounds__(256) kScan(const double* __restrict__ T,
                                             double* __restrict__ C) { // [256][NQ]
    int chain = blockIdx.x, t = threadIdx.x;
    const double* Tc = T + (size_t)chain * NQ;
    double v[16], tot = 0.0;
    #pragma unroll
    for (int m = 0; m < 16; ++m) { v[m] = Tc[t * 16 + m]; tot += v[m]; }
    __shared__ double sb[256];
    sb[t] = tot;
    __syncthreads();
    for (int off = 1; off < 256; off <<= 1) {
        double x = (t >= off) ? sb[t - off] : 0.0;
        __syncthreads();
        sb[t] += x;
        __syncthreads();
    }
    double run = sb[t] - tot;
    double* Cc = C + (size_t)chain * NQ;
    #pragma unroll
    for (int m = 0; m < 16; ++m) { Cc[t * 16 + m] = run; run += v[m]; }
}

// ---- kC: transposed synth. lane = sample, loop over harmonics -------------
// Window = half-frame (128 samples, 2 slots/lane), quarter-frame f64 anchors.
// Phase linearized: ph_rev = Crev + cnt*fs0rev + dfsrev*W (W = f32 lane scan
// of bit-exact weights). No cross-lane reduce; coalesced stores.
__global__ void __launch_bounds__(256) kC(const float* __restrict__ FS,
                                          const float* __restrict__ Aamp,
                                          const float* __restrict__ u,
                                          const double* __restrict__ C,
                                          float* __restrict__ out) {
    int t = threadIdx.x;
    int lane = t & 63, wv = t >> 6;
    int task = blockIdx.x * 4 + wv;       // 0..8191
    int fh = task & (NF2 - 1);
    int b  = task >> 11;
    int f  = fh >> 1;
    int chain_l = b * O + lane;           // lane-as-harmonic for loads

    // setup (lane = harmonic)
    const float* FSc = FS + chain_l * TF;
    const float* Ac  = Aamp + chain_l * TF;
    float fs0 = FSc[f], fs1 = FSc[f + 1];
    float a0  = Ac[f],  a1  = Ac[f + 1];
    const double* Cc = C + (size_t)chain_l * NQ + fh * 2;
    double c0 = Cc[0] * INV2PI64;
    double c1 = Cc[1] * INV2PI64;
    float vC0 = (float)(c0 - rint(c0));   // pre-wrapped anchor, revolutions
    float vC1 = (float)(c1 - rint(c1));
    float vF  = fs0 * INV2PI32;           // rev per sample
    float vD  = (fs1 - fs0) * INV2PI32;
    float vA  = a0;
    float vDA = a1 - a0;
    float vCor = (init32(u[chain_l]) - fs0) * INV2PI32;  // only for fh==0

    // geometry (lane = sample); bit-exact golden weights
    int n0 = fh * 128 + lane;
    float ff = (float)f;
    float pos0 = (float)n0 * C32POS;
    asm volatile("" : "+v"(pos0));
    float w0 = pos0 - ff;
    float pos1 = (float)(n0 + 64) * C32POS;
    asm volatile("" : "+v"(pos1));
    float w1 = pos1 - ff;

    // inclusive f32 scans of weights within each quarter
    float W0 = w0, W1 = w1;
    #pragma unroll
    for (int d = 1; d < 64; d <<= 1) {
        float s0 = __shfl_up(W0, d, 64);
        float s1 = __shfl_up(W1, d, 64);
        if (lane >= d) { W0 += s0; W1 += s1; }
    }
    float cntf = (float)(lane + 1);
    bool corr = (fh == 0);

    float acc0 = 0.0f, acc1 = 0.0f;
    #pragma unroll
    for (int o = 0; o < O; ++o) {
        float sF  = rl(vF,  o);
        float sD  = rl(vD,  o);
        float sC0 = rl(vC0, o);
        float sC1 = rl(vC1, o);
        float sA  = rl(vA,  o);
        float sDA = rl(vDA, o);
        if (corr) sC0 += rl(vCor, o);     // init replaces summand 0
        // slot 0
        float u0  = fmaf(W0, sD, sC0);
        float ph0 = fmaf(cntf, sF, u0);
        float am0 = fmaf(w0, sDA, sA);
        acc0 = fmaf(__builtin_amdgcn_sinf(fract32(ph0)), am0, acc0);
        // slot 1
        float u1  = fmaf(W1, sD, sC1);
        float ph1 = fmaf(cntf, sF, u1);
        float am1 = fmaf(w1, sDA, sA);
        acc1 = fmaf(__builtin_amdgcn_sinf(fract32(ph1)), am1, acc1);
    }
    size_t ob = (size_t)b * TOUT + fh * 128;
    out[ob + lane]      = acc0;           // coalesced 256B stores
    out[ob + 64 + lane] = acc1;
}

extern "C" void kernel_launch(void* const* d_in, const int* in_sizes, int n_in,
                              void* d_out, int out_size, void* d_ws, size_t ws_size,
                              hipStream_t stream) {
    const float* f0     = (const float*)d_in[0];
    const float* master = (const float*)d_in[1];
    const float* ov     = (const float*)d_in[2];
    const float* u      = (const float*)d_in[3];
    float* out = (float*)d_out;

    // ws: T (8MB f64) | C (8MB f64) | FS (1.05MB) | Aamp (1.05MB) = 18.9MB
    double* T    = (double*)d_ws;
    double* C    = T + (size_t)B * O * NQ;
    float*  FS   = (float*)(C + (size_t)B * O * NQ);
    float*  Aamp = FS + (size_t)B * O * TF;

    k1   <<<dim3(TF, B),      64,  0, stream>>>(f0, master, ov, FS, Aamp);
    kT   <<<dim3(NF, B),      256, 0, stream>>>(FS, u, T);
    kScan<<<B * O,            256, 0, stream>>>(T, C);
    kC   <<<(B * NF2) / 4,    256, 0, stream>>>(FS, Aamp, u, C, out);
}

// Round 14
// 52.036 us; speedup vs baseline: 2.7252x; 1.3655x over previous
//
#include <hip/hip_runtime.h>
#include <math.h>
#include <stdint.h>

#define B    4
#define O    64
#define TF   1025
#define NF   1024
#define NF2  2048      // half-frames (128 samples: kC window)
#define NQ   4096      // quarter-frames (64 samples: anchor granularity)
#define TOUT 262144

#define C32POS  ((float)(1024.0 / 262143.0))   // == 2^-8 + 2^-26 exactly
#define C2PI32  ((float)(2.0 * M_PI / 44100.0))
#define PI32    ((float)M_PI)
#define INV2PI32 ((float)(1.0 / (2.0 * M_PI)))
#define INV2PI64 0.15915494309189535

// fl32(x0*(1-w)) + fl32(x1*w), contraction-proof (numpy op order, no fma).
// At w==1.0 returns fs1 BIT-EXACTLY -> covers pos-round-up / clip edges.
__device__ __forceinline__ float lin32(float x0, float x1, float w) {
    float omw = 1.0f - w;
    float t1 = x0 * omw;
    float t2 = x1 * w;
    asm volatile("" : "+v"(t1), "+v"(t2));
    return t1 + t2;
}

__device__ __forceinline__ float init32(float uu) {
    return ((uu * 2.0f) - 1.0f) * PI32;   // fl32(3.14159265) == fl32(pi)
}

__device__ __forceinline__ float fract32(float x) {
#if __has_builtin(__builtin_amdgcn_fractf)
    return __builtin_amdgcn_fractf(x);
#else
    return x - floorf(x);
#endif
}

// ---- k1: bit-exact f32 fs table + frame amps (butterfly denominator) ------
__global__ void __launch_bounds__(64) k1(
        const float* __restrict__ f0, const float* __restrict__ master,
        const float* __restrict__ ov,
        float* __restrict__ FS, float* __restrict__ Aamp) {
    int f = blockIdx.x, b = blockIdx.y, o = threadIdx.x;
    float f0v = f0[b * TF + f];
    float fs  = (f0v * (float)(o + 1)) * C2PI32;
    FS[(b * O + o) * TF + f] = fs;
    float val = (fs > PI32) ? 0.0f : ov[(b * O + o) * TF + f];
    float den = val;
    #pragma unroll
    for (int d = 32; d; d >>= 1) den += __shfl_xor(den, d, 64);
    Aamp[(b * O + o) * TF + f] = (val / den) * master[b * TF + f];
}

// ---- kT: per-QUARTER-frame f64 totals of bit-exact f32 summands -----------
__global__ void __launch_bounds__(256) kT(const float* __restrict__ FS,
                                          const float* __restrict__ u,
                                          double* __restrict__ T) { // [256][NQ]
    int f = blockIdx.x, b = blockIdx.y;
    int t = threadIdx.x;
    int o = t & 63, q = t >> 6;
    int chain = b * O + o;
    float fs0 = FS[chain * TF + f], fs1 = FS[chain * TF + f + 1];
    float ff = (float)f;
    float fn = (float)(f * 256 + q * 64);
    double s = 0.0;
    #pragma unroll 8
    for (int k = 0; k < 64; ++k) {
        float pos = fn * C32POS;
        asm volatile("" : "+v"(pos));          // forbid mul+sub fma-contraction
        float w = pos - ff;
        s += (double)lin32(fs0, fs1, w);       // w==1.0 edge -> fs1 exact
        fn += 1.0f;
    }
    if (f == 0 && q == 0)                      // replace summand 0 (==fs0) by init
        s = s - (double)fs0 + (double)init32(u[chain]);
    T[(size_t)chain * NQ + f * 4 + q] = s;
}

// ---- kScan: per-chain exclusive scan of 4096 quarter totals (f64) ---------
__global__ void __launch_bounds__(256) kScan(const double* __restrict__ T,
                                             double* __restrict__ C) { // [256][NQ]
    int chain = blockIdx.x, t = threadIdx.x;
    const double* Tc = T + (size_t)chain * NQ;
    double v[16], tot = 0.0;
    #pragma unroll
    for (int m = 0; m < 16; ++m) { v[m] = Tc[t * 16 + m]; tot += v[m]; }
    __shared__ double sb[256];
    sb[t] = tot;
    __syncthreads();
    for (int off = 1; off < 256; off <<= 1) {
        double x = (t >= off) ? sb[t - off] : 0.0;
        __syncthreads();
        sb[t] += x;
        __syncthreads();
    }
    double run = sb[t] - tot;
    double* Cc = C + (size_t)chain * NQ;
    #pragma unroll
    for (int m = 0; m < 16; ++m) { Cc[t * 16 + m] = run; run += v[m]; }
}

// ---- kC: transposed synth, LDS-broadcast scalars (no readlane) ------------
// lane = sample (2 slots), o-loop reads per-harmonic scalars via uniform
// ds_read_b128/b64 broadcast. Per-(n,o) math op-for-op identical to R13.
__global__ void __launch_bounds__(256, 8) kC(const float* __restrict__ FS,
                                             const float* __restrict__ Aamp,
                                             const float* __restrict__ u,
                                             const double* __restrict__ C,
                                             float* __restrict__ out) {
    __shared__ float scal[4][O][8];       // [wave][harmonic][C0,C1,F,D,A,DA,-,-]
    int t = threadIdx.x;
    int lane = t & 63, wv = t >> 6;
    int task = blockIdx.x * 4 + wv;       // 0..8191
    int fh = task & (NF2 - 1);
    int b  = task >> 11;
    int f  = fh >> 1;
    int chain_l = b * O + lane;           // lane-as-harmonic for setup loads

    const float* FSc = FS + chain_l * TF;
    const float* Ac  = Aamp + chain_l * TF;
    float fs0 = FSc[f], fs1 = FSc[f + 1];
    float a0  = Ac[f],  a1  = Ac[f + 1];
    const double* Cc = C + (size_t)chain_l * NQ + fh * 2;
    double c0 = Cc[0] * INV2PI64;
    double c1 = Cc[1] * INV2PI64;
    float vC0 = (float)(c0 - rint(c0));   // pre-wrapped anchors, revolutions
    float vC1 = (float)(c1 - rint(c1));
    float vF  = fs0 * INV2PI32;           // rev per sample
    float vD  = (fs1 - fs0) * INV2PI32;
    if (fh == 0)                          // fold init correction (bit == R13)
        vC0 = vC0 + (init32(u[chain_l]) - fs0) * INV2PI32;
    *(float4*)&scal[wv][lane][0] = make_float4(vC0, vC1, vF, vD);
    *(float2*)&scal[wv][lane][4] = make_float2(a0, a1 - a0);

    // geometry (lane = sample); bit-exact golden weights
    int n0 = fh * 128 + lane;
    float ff = (float)f;
    float pos0 = (float)n0 * C32POS;
    asm volatile("" : "+v"(pos0));
    float w0 = pos0 - ff;
    float pos1 = (float)(n0 + 64) * C32POS;
    asm volatile("" : "+v"(pos1));
    float w1 = pos1 - ff;

    // inclusive f32 scans of weights within each quarter (as R13)
    float W0 = w0, W1 = w1;
    #pragma unroll
    for (int d = 1; d < 64; d <<= 1) {
        float s0 = __shfl_up(W0, d, 64);
        float s1 = __shfl_up(W1, d, 64);
        if (lane >= d) { W0 += s0; W1 += s1; }
    }
    float cntf = (float)(lane + 1);
    __syncthreads();                      // LDS table visible

    float acc0 = 0.0f, acc1 = 0.0f;
    #pragma unroll 8
    for (int o = 0; o < O; ++o) {
        float4 s4 = *(const float4*)&scal[wv][o][0];   // uniform -> broadcast
        float2 s2 = *(const float2*)&scal[wv][o][4];
        float u0  = fmaf(W0, s4.w, s4.x);
        float ph0 = fmaf(cntf, s4.z, u0);
        float am0 = fmaf(w0, s2.y, s2.x);
        acc0 = fmaf(__builtin_amdgcn_sinf(fract32(ph0)), am0, acc0);
        float u1  = fmaf(W1, s4.w, s4.y);
        float ph1 = fmaf(cntf, s4.z, u1);
        float am1 = fmaf(w1, s2.y, s2.x);
        acc1 = fmaf(__builtin_amdgcn_sinf(fract32(ph1)), am1, acc1);
    }
    size_t ob = (size_t)b * TOUT + fh * 128;
    out[ob + lane]      = acc0;           // coalesced 256B stores
    out[ob + 64 + lane] = acc1;
}

extern "C" void kernel_launch(void* const* d_in, const int* in_sizes, int n_in,
                              void* d_out, int out_size, void* d_ws, size_t ws_size,
                              hipStream_t stream) {
    const float* f0     = (const float*)d_in[0];
    const float* master = (const float*)d_in[1];
    const float* ov     = (const float*)d_in[2];
    const float* u      = (const float*)d_in[3];
    float* out = (float*)d_out;

    // ws: T (8MB f64) | C (8MB f64) | FS (1.05MB) | Aamp (1.05MB) = 18.9MB
    double* T    = (double*)d_ws;
    double* C    = T + (size_t)B * O * NQ;
    float*  FS   = (float*)(C + (size_t)B * O * NQ);
    float*  Aamp = FS + (size_t)B * O * TF;

    k1   <<<dim3(TF, B),      64,  0, stream>>>(f0, master, ov, FS, Aamp);
    kT   <<<dim3(NF, B),      256, 0, stream>>>(FS, u, T);
    kScan<<<B * O,            256, 0, stream>>>(T, C);
    kC   <<<(B * NF2) / 4,    256, 0, stream>>>(FS, Aamp, u, C, out);
}

// Round 15
// 47.715 us; speedup vs baseline: 2.9720x; 1.0906x over previous
//
#include <hip/hip_runtime.h>
#include <math.h>
#include <stdint.h>

#define B    4
#define O    64
#define TF   1025
#define NF   1024
#define NF2  2048      // half-frames (128 samples: kC window)
#define NQ   4096      // quarter-frames (64 samples: anchor granularity)
#define TOUT 262144

#define C32POS  ((float)(1024.0 / 262143.0))   // == 2^-8 + 2^-26 exactly
#define C2PI32  ((float)(2.0 * M_PI / 44100.0))
#define PI32    ((float)M_PI)
#define INV2PI32 ((float)(1.0 / (2.0 * M_PI)))
#define INV2PI64 0.15915494309189535

// fl32(x0*(1-w)) + fl32(x1*w), contraction-proof (numpy op order, no fma).
// At w==1.0 returns fs1 BIT-EXACTLY -> covers pos-round-up / clip edges.
__device__ __forceinline__ float lin32(float x0, float x1, float w) {
    float omw = 1.0f - w;
    float t1 = x0 * omw;
    float t2 = x1 * w;
    asm volatile("" : "+v"(t1), "+v"(t2));
    return t1 + t2;
}

__device__ __forceinline__ float init32(float uu) {
    return ((uu * 2.0f) - 1.0f) * PI32;   // fl32(3.14159265) == fl32(pi)
}

__device__ __forceinline__ float fract32(float x) {
#if __has_builtin(__builtin_amdgcn_fractf)
    return __builtin_amdgcn_fractf(x);
#else
    return x - floorf(x);
#endif
}

// ---- k1: frame amps only (butterfly denominator); Aamp layout [TF][B][O] --
__global__ void __launch_bounds__(64) k1(
        const float* __restrict__ f0, const float* __restrict__ master,
        const float* __restrict__ ov, float* __restrict__ Aamp) {
    int f = blockIdx.x, b = blockIdx.y, o = threadIdx.x;
    float f0v = f0[b * TF + f];
    float fs  = (f0v * (float)(o + 1)) * C2PI32;
    float val = (fs > PI32) ? 0.0f : ov[(b * O + o) * TF + f];
    float den = val;
    #pragma unroll
    for (int d = 32; d; d >>= 1) den += __shfl_xor(den, d, 64);
    Aamp[(f * B + b) * O + o] = (val / den) * master[b * TF + f];
}

// ---- kT: per-QUARTER-frame f64 totals; w staged in LDS (bit-identical) ----
__global__ void __launch_bounds__(256) kT(const float* __restrict__ f0,
                                          const float* __restrict__ u,
                                          double* __restrict__ T) { // [256][NQ]
    __shared__ float wlds[4][64];
    int f = blockIdx.x, b = blockIdx.y;
    int t = threadIdx.x;
    int o = t & 63, q = t >> 6;
    {   // lane o computes w for sample k=o of quarter q (same bits as before)
        float pos = (float)(f * 256 + q * 64 + o) * C32POS;
        asm volatile("" : "+v"(pos));          // forbid fma contraction
        wlds[q][o] = pos - (float)f;
    }
    __syncthreads();
    int chain = b * O + o;
    float f00 = f0[b * TF + f], f01 = f0[b * TF + f + 1];
    float hm  = (float)(o + 1);
    float fs0 = (f00 * hm) * C2PI32;           // identical expression to k1
    float fs1 = (f01 * hm) * C2PI32;
    double s = 0.0;
    #pragma unroll 8
    for (int k = 0; k < 64; ++k)
        s += (double)lin32(fs0, fs1, wlds[q][k]);   // w==1.0 edge -> fs1 exact
    if (f == 0 && q == 0)                      // replace summand 0 (==fs0)
        s = s - (double)fs0 + (double)init32(u[chain]);
    T[(size_t)chain * NQ + f * 4 + q] = s;
}

// ---- kScan: per-chain exclusive scan of 4096 quarter totals (f64) ---------
__global__ void __launch_bounds__(256) kScan(const double* __restrict__ T,
                                             double* __restrict__ C) { // [256][NQ]
    int chain = blockIdx.x, t = threadIdx.x;
    const double* Tc = T + (size_t)chain * NQ;
    double v[16], tot = 0.0;
    #pragma unroll
    for (int m = 0; m < 16; ++m) { v[m] = Tc[t * 16 + m]; tot += v[m]; }
    __shared__ double sb[256];
    sb[t] = tot;
    __syncthreads();
    for (int off = 1; off < 256; off <<= 1) {
        double x = (t >= off) ? sb[t - off] : 0.0;
        __syncthreads();
        sb[t] += x;
        __syncthreads();
    }
    double run = sb[t] - tot;
    double* Cc = C + (size_t)chain * NQ;
    #pragma unroll
    for (int m = 0; m < 16; ++m) { Cc[t * 16 + m] = run; run += v[m]; }
}

// ---- kC: transposed synth, LDS-broadcast scalars; no spills ---------------
// lane = sample (2 slots), o-loop reads per-harmonic scalars via uniform
// ds_read broadcast. Per-(n,o) math op-for-op identical to R13/R14.
__global__ void __launch_bounds__(256, 4) kC(const float* __restrict__ f0,
                                             const float* __restrict__ Aamp,
                                             const float* __restrict__ u,
                                             const double* __restrict__ C,
                                             float* __restrict__ out) {
    __shared__ float scal[4][O][8];       // [wave][harmonic][C0,C1,F,D,A,DA,-,-]
    int t = threadIdx.x;
    int lane = t & 63, wv = t >> 6;
    int task = blockIdx.x * 4 + wv;       // 0..8191
    int fh = task & (NF2 - 1);
    int b  = task >> 11;
    int f  = fh >> 1;
    int chain_l = b * O + lane;           // lane-as-harmonic for setup

    // per-harmonic scalars (fs computed locally, bit-identical to k1/kT)
    float f00 = f0[b * TF + f], f01 = f0[b * TF + f + 1];
    float hm  = (float)(lane + 1);
    float fs0 = (f00 * hm) * C2PI32;
    float fs1 = (f01 * hm) * C2PI32;
    float a0  = Aamp[(f * B + b) * O + lane];        // coalesced
    float a1  = Aamp[((f + 1) * B + b) * O + lane];  // coalesced
    const double* Cc = C + (size_t)chain_l * NQ + fh * 2;
    double c0 = Cc[0] * INV2PI64;
    double c1 = Cc[1] * INV2PI64;
    float vC0 = (float)(c0 - rint(c0));   // pre-wrapped anchors, revolutions
    float vC1 = (float)(c1 - rint(c1));
    float vF  = fs0 * INV2PI32;           // rev per sample
    float vD  = (fs1 - fs0) * INV2PI32;
    if (fh == 0)                          // fold init correction (bit == R14)
        vC0 = vC0 + (init32(u[chain_l]) - fs0) * INV2PI32;
    *(float4*)&scal[wv][lane][0] = make_float4(vC0, vC1, vF, vD);
    *(float2*)&scal[wv][lane][4] = make_float2(a0, a1 - a0);

    // geometry (lane = sample); bit-exact golden weights
    int n0 = fh * 128 + lane;
    float ff = (float)f;
    float pos0 = (float)n0 * C32POS;
    asm volatile("" : "+v"(pos0));
    float w0 = pos0 - ff;
    float pos1 = (float)(n0 + 64) * C32POS;
    asm volatile("" : "+v"(pos1));
    float w1 = pos1 - ff;

    // inclusive f32 scans of weights within each quarter (as R13/R14)
    float W0 = w0, W1 = w1;
    #pragma unroll
    for (int d = 1; d < 64; d <<= 1) {
        float s0 = __shfl_up(W0, d, 64);
        float s1 = __shfl_up(W1, d, 64);
        if (lane >= d) { W0 += s0; W1 += s1; }
    }
    float cntf = (float)(lane + 1);
    __syncthreads();                      // LDS table visible

    float acc0 = 0.0f, acc1 = 0.0f;
    #pragma unroll 4
    for (int o = 0; o < O; ++o) {
        float4 s4 = *(const float4*)&scal[wv][o][0];   // uniform -> broadcast
        float2 s2 = *(const float2*)&scal[wv][o][4];
        float u0  = fmaf(W0, s4.w, s4.x);
        float ph0 = fmaf(cntf, s4.z, u0);
        float am0 = fmaf(w0, s2.y, s2.x);
        acc0 = fmaf(__builtin_amdgcn_sinf(fract32(ph0)), am0, acc0);
        float u1  = fmaf(W1, s4.w, s4.y);
        float ph1 = fmaf(cntf, s4.z, u1);
        float am1 = fmaf(w1, s2.y, s2.x);
        acc1 = fmaf(__builtin_amdgcn_sinf(fract32(ph1)), am1, acc1);
    }
    size_t ob = (size_t)b * TOUT + fh * 128;
    out[ob + lane]      = acc0;           // coalesced 256B stores
    out[ob + 64 + lane] = acc1;
}

extern "C" void kernel_launch(void* const* d_in, const int* in_sizes, int n_in,
                              void* d_out, int out_size, void* d_ws, size_t ws_size,
                              hipStream_t stream) {
    const float* f0     = (const float*)d_in[0];
    const float* master = (const float*)d_in[1];
    const float* ov     = (const float*)d_in[2];
    const float* u      = (const float*)d_in[3];
    float* out = (float*)d_out;

    // ws: T (8MB f64) | C (8MB f64) | Aamp (1.05MB)
    double* T    = (double*)d_ws;
    double* C    = T + (size_t)B * O * NQ;
    float*  Aamp = (float*)(C + (size_t)B * O * NQ);

    k1   <<<dim3(TF, B),      64,  0, stream>>>(f0, master, ov, Aamp);
    kT   <<<dim3(NF, B),      256, 0, stream>>>(f0, u, T);
    kScan<<<B * O,            256, 0, stream>>>(T, C);
    kC   <<<(B * NF2) / 4,    256, 0, stream>>>(f0, Aamp, u, C, out);
}